// Round 6
// baseline (418.397 us; speedup 1.0000x reference)
//
#include <hip/hip_runtime.h>

#define NROWS 8192
#define BBND  32
#define CBND  512
#define JQ    2048            // j-range per block
#define JSTEP 32
#define NTQ   (JQ / JSTEP)    // 64 iters
#define ABUFB 4096            // A LDS buffer bytes (64 rows x 64B)

typedef unsigned short u16;
typedef unsigned int   u32;
typedef __bf16 bf16x8 __attribute__((ext_vector_type(8)));
typedef float  f32x4  __attribute__((ext_vector_type(4)));
typedef float  f32x16 __attribute__((ext_vector_type(16)));
typedef u32    u32x4  __attribute__((ext_vector_type(4)));
typedef u32    u32x2  __attribute__((ext_vector_type(2)));

#define ZERO4  (f32x4){0.f,0.f,0.f,0.f}
#define ZERO16 (f32x16){0.f,0.f,0.f,0.f,0.f,0.f,0.f,0.f,0.f,0.f,0.f,0.f,0.f,0.f,0.f,0.f}

static __device__ inline u16 f2bf(float f) {
    unsigned u = __builtin_bit_cast(unsigned, f);
    unsigned r = (u + 0x7FFFu + ((u >> 16) & 1u)) >> 16;
    return (u16)r;
}

static __device__ inline float pow14(float base) {
    return __builtin_amdgcn_exp2f(1.4f * __builtin_amdgcn_logf(base));
}

static __device__ inline float adj_eval(float dot, float sij) {
    float x = fabsf(2.f * dot - sij);
    float base = fmaxf(1.f - x * (1.f / 32.f), 0.f);
    return pow14(base);
}

static __device__ inline float sigmoidf_fast(float v) {
    float e = __builtin_amdgcn_exp2f(-1.44269504f * v);
    return 1.f / (1.f + e);
}

static __device__ inline u32 cvtpk(float a, float b) {
    u32 r;
    asm("v_cvt_pk_bf16_f32 %0, %1, %2" : "=v"(r) : "v"(a), "v"(b));
    return r;
}

static __device__ inline f32x4 MFMA16(bf16x8 a, bf16x8 b, f32x4 c) {
    return __builtin_amdgcn_mfma_f32_16x16x32_bf16(a, b, c, 0, 0, 0);
}
static __device__ inline f32x16 MFMA32(bf16x8 a, bf16x8 b, f32x16 c) {
    return __builtin_amdgcn_mfma_f32_32x32x16_bf16(a, b, c, 0, 0, 0);
}

// ---------------- prep: row sums of bbn + bf16 copy ----------------
__global__ __launch_bounds__(256) void k_prep_rows(const float* __restrict__ bbn,
                                                   float* __restrict__ s,
                                                   u16* __restrict__ bbn_bf) {
    int i = blockIdx.x * 256 + threadIdx.x;
    if (i >= NROWS) return;
    const f32x4* row = reinterpret_cast<const f32x4*>(bbn + i * BBND);
    float sum = 0.f;
    u16* dst = bbn_bf + i * BBND;
#pragma unroll
    for (int q = 0; q < 8; ++q) {
        f32x4 v = row[q];
#pragma unroll
        for (int e = 0; e < 4; ++e) {
            sum += v[e];
            dst[q * 4 + e] = f2bf(v[e]);
        }
    }
    s[i] = sum;
}

// ---------------- prep: W transpose -> bf16 ----------------
__global__ __launch_bounds__(256) void k_prep_wt(const float* __restrict__ W,
                                                 u16* __restrict__ WT) {
    int idx = blockIdx.x * 256 + threadIdx.x;   // over 512*512
    int c = idx >> 9, k = idx & 511;
    WT[idx] = f2bf(W[k * CBND + c]);            // WT[c][k]
}

// ---------------- degree: d_i = sum_j adj_ij ; dinv = rsqrt(d+eps) ----------------
__global__ __launch_bounds__(512) void k_deg(const u16* __restrict__ bbn_bf,
                                             const float* __restrict__ s,
                                             float* __restrict__ dinv) {
    __shared__ float part[8][16];
    int ibase = blockIdx.x * 16;
    int tid = threadIdx.x;
    int w = tid >> 6, l = tid & 63, lg = l >> 4, lr = l & 15;

    bf16x8 afrag = *reinterpret_cast<const bf16x8*>(bbn_bf + (ibase + lr) * BBND + lg * 8);
    float si[4];
#pragma unroll
    for (int r = 0; r < 4; ++r) si[r] = s[ibase + lg * 4 + r];

    float dacc[4] = {0.f, 0.f, 0.f, 0.f};
    int j0 = w * (NROWS / 8);
    for (int jt = 0; jt < NROWS / 8; jt += 16) {
        int jb = j0 + jt;
        bf16x8 bfrag = *reinterpret_cast<const bf16x8*>(bbn_bf + (jb + lr) * BBND + lg * 8);
        f32x4 dot = MFMA16(afrag, bfrag, ZERO4);
        float sj = s[jb + lr];
#pragma unroll
        for (int r = 0; r < 4; ++r) dacc[r] += adj_eval(dot[r], si[r] + sj);
    }
#pragma unroll
    for (int off = 1; off < 16; off <<= 1)
#pragma unroll
        for (int r = 0; r < 4; ++r) dacc[r] += __shfl_xor(dacc[r], off, 64);

    if (lr == 0) {
#pragma unroll
        for (int r = 0; r < 4; ++r) part[w][lg * 4 + r] = dacc[r];
    }
    __syncthreads();
    if (tid < 16) {
        float d = 0.f;
#pragma unroll
        for (int q = 0; q < 8; ++q) d += part[q][tid];
        dinv[ibase + tid] = rsqrtf(d + 1e-8f);
    }
}

// ---------------- fc: gT[c][j] = dinv_j * (cbn@W + b)[j][c], bf16 ----------------
__global__ __launch_bounds__(256) void k_fc(const float* __restrict__ cbn,
                                            const u16* __restrict__ WT,
                                            const float* __restrict__ bvec,
                                            const float* __restrict__ dinv,
                                            u16* __restrict__ gT) {
    int bid = blockIdx.x;
    int cb = bid & 7, jb = bid >> 3;
    int tid = threadIdx.x, w = tid >> 6, l = tid & 63, lg = l >> 4, lr = l & 15;
    int crow = cb * 64 + w * 16;
    int jcol = jb * 64;

    f32x4 acc[4];
#pragma unroll
    for (int f = 0; f < 4; ++f) acc[f] = ZERO4;

    for (int k0 = 0; k0 < CBND; k0 += 32) {
        bf16x8 afrag = *reinterpret_cast<const bf16x8*>(WT + (crow + lr) * CBND + k0 + lg * 8);
#pragma unroll
        for (int f = 0; f < 4; ++f) {
            const float* src = cbn + (jcol + f * 16 + lr) * CBND + k0 + lg * 8;
            f32x4 v0 = *reinterpret_cast<const f32x4*>(src);
            f32x4 v1 = *reinterpret_cast<const f32x4*>(src + 4);
            bf16x8 bfrag;
#pragma unroll
            for (int e = 0; e < 4; ++e) { bfrag[e] = (__bf16)v0[e]; bfrag[e + 4] = (__bf16)v1[e]; }
            acc[f] = MFMA16(afrag, bfrag, acc[f]);
        }
    }
#pragma unroll
    for (int f = 0; f < 4; ++f) {
#pragma unroll
        for (int r = 0; r < 4; ++r) {
            int c = crow + lg * 4 + r;
            int j = jcol + f * 16 + lr;
            float val = acc[f][r] + bvec[c];
            gT[c * NROWS + j] = f2bf(val * dinv[j]);
        }
    }
}

// ---------------- conv: atomic-accumulate sum_j adj_ij * gT[:,j] into out ----------------
// Round-4 structure (proved 1-ULP correct) with B-LDS DELETED: B fragments come
// straight from gT (L2-resident 2MB slice per XCD-pair) via distance-1 register
// prefetch. A(adj) stays in dbuf LDS with the CORRECTED swizzle:
// phys16Bslot = logical ^ ((row>>1)&3)  -> bank-quad (4*row+slot)%8 distinct
// across 8 consecutive rows => conflict-free b128 (old row&3 collided r,r+4).

#define LOADB(T, R) { \
    const char* p = gB + (T) * 64; \
    R##0 = *reinterpret_cast<const u32x4*>(p); \
    R##1 = *reinterpret_cast<const u32x4*>(p + 0x80000); \
    R##2 = *reinterpret_cast<const u32x4*>(p + 0x100000); \
    R##3 = *reinterpret_cast<const u32x4*>(p + 0x180000); \
    R##4 = *reinterpret_cast<const u32x4*>(p + 32); \
    R##5 = *reinterpret_cast<const u32x4*>(p + 0x80000 + 32); \
    R##6 = *reinterpret_cast<const u32x4*>(p + 0x100000 + 32); \
    R##7 = *reinterpret_cast<const u32x4*>(p + 0x180000 + 32); \
}

#define GEN(T, WB) { \
    int jg = jbase + (T) * JSTEP + jh2 * 16; \
    bf16x8 fJ = *reinterpret_cast<const bf16x8*>(bbn_bf + (jg + lr) * BBND + lg * 8); \
    f32x4 sj = *reinterpret_cast<const f32x4*>(s + jg + lg * 4); \
    f32x4 dot = MFMA16(fJ, fragI, ZERO4); \
    u32 p0 = cvtpk(adj_eval(dot[0], si + sj[0]), adj_eval(dot[1], si + sj[1])); \
    u32 p1 = cvtpk(adj_eval(dot[2], si + sj[2]), adj_eval(dot[3], si + sj[3])); \
    *reinterpret_cast<u32x2*>(Ab + (WB) * ABUFB + gw) = (u32x2){p0, p1}; \
}

#define CONV(RB, R) { \
    const char* Ar = Ab + (RB) * ABUFB; \
    bf16x8 a0 = *reinterpret_cast<const bf16x8*>(Ar + aoff0); \
    bf16x8 a1 = *reinterpret_cast<const bf16x8*>(Ar + aoff1); \
    acc0 = MFMA32(a0, __builtin_bit_cast(bf16x8, R##0), acc0); \
    acc1 = MFMA32(a0, __builtin_bit_cast(bf16x8, R##1), acc1); \
    acc2 = MFMA32(a0, __builtin_bit_cast(bf16x8, R##2), acc2); \
    acc3 = MFMA32(a0, __builtin_bit_cast(bf16x8, R##3), acc3); \
    acc0 = MFMA32(a1, __builtin_bit_cast(bf16x8, R##4), acc0); \
    acc1 = MFMA32(a1, __builtin_bit_cast(bf16x8, R##5), acc1); \
    acc2 = MFMA32(a1, __builtin_bit_cast(bf16x8, R##6), acc2); \
    acc3 = MFMA32(a1, __builtin_bit_cast(bf16x8, R##7), acc3); \
}

#define EPI(ACC, NC) { \
    _Pragma("unroll") \
    for (int reg = 0; reg < 16; ++reg) { \
        int rowD = (reg & 3) + 8 * (reg >> 2) + 4 * lh; \
        unsafeAtomicAdd(out + (long)(ibase + iw * 32 + rowD) * CBND \
                            + cw * 128 + (NC) * 32 + l31, ACC[reg]); \
    } \
}

__global__ __launch_bounds__(512, 2) void k_conv(const u16* __restrict__ bbn_bf,
                                                 const float* __restrict__ s,
                                                 const u16* __restrict__ gT,
                                                 float* __restrict__ out) {
    __shared__ __align__(16) u16 Alds[2][64 * 32];

    int bx = blockIdx.x;
    int xcd = bx & 7;
    int jq = xcd >> 1;                 // XCD pair shares one 2MB gT j-slice (L2-fit)
    int it = (bx >> 3) + 64 * (xcd & 1);  // 0..127
    int ibase = it * 64;
    int jbase = jq * JQ;

    int tid = threadIdx.x;
    int w = tid >> 6, l = tid & 63;
    int lr = l & 15, lg = l >> 4, l31 = l & 31, lh = l >> 5;
    int iw = w & 1, cw = w >> 1;       // acc wave tile: 32i x 128c
    int iqg = w & 3, jh2 = w >> 2;     // gen wave tile: 16i x 16j

    // gen hoists
    bf16x8 fragI = *reinterpret_cast<const bf16x8*>(bbn_bf + (ibase + iqg * 16 + lr) * BBND + lg * 8);
    float si = s[ibase + iqg * 16 + lr];

    char* Ab = (char*)&Alds[0][0];
    const char* gTb = (const char*)gT;

    // B global base: lane owns c-row cw*128 + l31 (+nc*32 via +0x80000 steps), j-half lh
    const char* gB = gTb + (long)(cw * 128 + l31) * 16384 + (long)jbase * 2 + lh * 16;

    // A-frag reads (corrected swizzle)
    int arow = iw * 32 + l31;
    int sa = (arow >> 1) & 3;
    int aoff0 = arow * 64 + (((lh)     ^ sa) << 4);
    int aoff1 = arow * 64 + (((2 + lh) ^ sa) << 4);

    // gen write: row = iqg*16+lr, logical slot jh2*2+(lg>>1), byte +(lg&1)*8
    int grow = iqg * 16 + lr;
    int gw = grow * 64 + ((((jh2 * 2) + (lg >> 1)) ^ ((grow >> 1) & 3)) << 4) + (lg & 1) * 8;

    f32x16 acc0 = ZERO16, acc1 = ZERO16, acc2 = ZERO16, acc3 = ZERO16;

    u32x4 rA0, rA1, rA2, rA3, rA4, rA5, rA6, rA7;
    u32x4 rB0, rB1, rB2, rB3, rB4, rB5, rB6, rB7;

    // prologue: A(0) into buf0, B(0) into rA
    GEN(0, 0);
    LOADB(0, rA);
    __syncthreads();

    for (int t2 = 0; t2 < NTQ; t2 += 2) {
        // iter t2: rA = B(t2), buf0 = A(t2)
        LOADB(t2 + 1, rB);
        GEN(t2 + 1, 1);
        CONV(0, rA);
        __syncthreads();
        // iter t2+1: rB = B(t2+1), buf1 = A(t2+1)
        int tn = (t2 + 2 < NTQ) ? t2 + 2 : NTQ - 1;   // tail: redundant, never read
        LOADB(tn, rA);
        GEN(tn, 0);
        CONV(1, rB);
        __syncthreads();
    }

    EPI(acc0, 0);  EPI(acc1, 1);  EPI(acc2, 2);  EPI(acc3, 3);
}

// ---------------- sigmoid epilogue: out = sigmoid(dinv_i * out), in place ----------------
__global__ __launch_bounds__(256) void k_sig(const float* __restrict__ dinv,
                                             float* __restrict__ out) {
    int idx = blockIdx.x * 256 + threadIdx.x;   // f32x4 index; 1,048,576 total
    float di = dinv[idx >> 7];
    f32x4 v = *reinterpret_cast<const f32x4*>(out + idx * 4);
#pragma unroll
    for (int e = 0; e < 4; ++e) v[e] = sigmoidf_fast(v[e] * di);
    *reinterpret_cast<f32x4*>(out + idx * 4) = v;
}

extern "C" void kernel_launch(void* const* d_in, const int* in_sizes, int n_in,
                              void* d_out, int out_size, void* d_ws, size_t ws_size,
                              hipStream_t stream) {
    const float* bbn = (const float*)d_in[0];   // [8192,32]
    const float* cbn = (const float*)d_in[1];   // [8192,512]
    const float* W   = (const float*)d_in[2];   // [512,512]
    const float* b   = (const float*)d_in[3];   // [512]
    float* out = (float*)d_out;                 // [8192,512] f32

    char* ws = (char*)d_ws;
    float* s      = (float*)ws;  ws += NROWS * 4;
    float* dinv   = (float*)ws;  ws += NROWS * 4;
    u16* bbn_bf   = (u16*)ws;    ws += NROWS * BBND * 2;
    u16* WT       = (u16*)ws;    ws += CBND * CBND * 2;
    u16* gT       = (u16*)ws;    ws += CBND * NROWS * 2;

    hipMemsetAsync(d_out, 0, (size_t)out_size * sizeof(float), stream);
    k_prep_rows<<<NROWS / 256, 256, 0, stream>>>(bbn, s, bbn_bf);
    k_prep_wt<<<(CBND * CBND) / 256, 256, 0, stream>>>(W, WT);
    k_deg<<<NROWS / 16, 512, 0, stream>>>(bbn_bf, s, dinv);
    k_fc<<<(NROWS / 64) * (CBND / 64), 256, 0, stream>>>(cbn, WT, b, dinv, gT);
    k_conv<<<(NROWS / 64) * 4, 512, 0, stream>>>(bbn_bf, s, gT, out);
    k_sig<<<(NROWS * CBND / 4) / 256, 256, 0, stream>>>(dinv, out);
}

// Round 7
// 289.550 us; speedup vs baseline: 1.4450x; 1.4450x over previous
//
#include <hip/hip_runtime.h>

#define NROWS 8192
#define BBND  32
#define CBND  512
#define JQ    1024            // j-range per block (8 slices)
#define JSTEP 32
#define NTQ   (JQ / JSTEP)    // 32 iters
#define ABUFB 4096            // A LDS buffer bytes (64 rows x 64B)

typedef unsigned short u16;
typedef unsigned int   u32;
typedef __bf16 bf16x8 __attribute__((ext_vector_type(8)));
typedef float  f32x4  __attribute__((ext_vector_type(4)));
typedef float  f32x16 __attribute__((ext_vector_type(16)));
typedef u32    u32x4  __attribute__((ext_vector_type(4)));
typedef u32    u32x2  __attribute__((ext_vector_type(2)));

#define ZERO4  (f32x4){0.f,0.f,0.f,0.f}
#define ZERO16 (f32x16){0.f,0.f,0.f,0.f,0.f,0.f,0.f,0.f,0.f,0.f,0.f,0.f,0.f,0.f,0.f,0.f}

static __device__ inline u16 f2bf(float f) {
    unsigned u = __builtin_bit_cast(unsigned, f);
    unsigned r = (u + 0x7FFFu + ((u >> 16) & 1u)) >> 16;
    return (u16)r;
}

static __device__ inline float pow14(float base) {
    return __builtin_amdgcn_exp2f(1.4f * __builtin_amdgcn_logf(base));
}

static __device__ inline float adj_eval(float dot, float sij) {
    float x = fabsf(2.f * dot - sij);
    float base = fmaxf(1.f - x * (1.f / 32.f), 0.f);
    return pow14(base);
}

static __device__ inline float sigmoidf_fast(float v) {
    float e = __builtin_amdgcn_exp2f(-1.44269504f * v);
    return 1.f / (1.f + e);
}

static __device__ inline u32 cvtpk(float a, float b) {
    u32 r;
    asm("v_cvt_pk_bf16_f32 %0, %1, %2" : "=v"(r) : "v"(a), "v"(b));
    return r;
}

static __device__ inline f32x4 MFMA16(bf16x8 a, bf16x8 b, f32x4 c) {
    return __builtin_amdgcn_mfma_f32_16x16x32_bf16(a, b, c, 0, 0, 0);
}
static __device__ inline f32x16 MFMA32(bf16x8 a, bf16x8 b, f32x16 c) {
    return __builtin_amdgcn_mfma_f32_32x32x16_bf16(a, b, c, 0, 0, 0);
}

// ---------------- prep: row sums of bbn + bf16 copy ----------------
__global__ __launch_bounds__(256) void k_prep_rows(const float* __restrict__ bbn,
                                                   float* __restrict__ s,
                                                   u16* __restrict__ bbn_bf) {
    int i = blockIdx.x * 256 + threadIdx.x;
    if (i >= NROWS) return;
    const f32x4* row = reinterpret_cast<const f32x4*>(bbn + i * BBND);
    float sum = 0.f;
    u16* dst = bbn_bf + i * BBND;
#pragma unroll
    for (int q = 0; q < 8; ++q) {
        f32x4 v = row[q];
#pragma unroll
        for (int e = 0; e < 4; ++e) {
            sum += v[e];
            dst[q * 4 + e] = f2bf(v[e]);
        }
    }
    s[i] = sum;
}

// ---------------- prep: W transpose -> bf16 ----------------
__global__ __launch_bounds__(256) void k_prep_wt(const float* __restrict__ W,
                                                 u16* __restrict__ WT) {
    int idx = blockIdx.x * 256 + threadIdx.x;   // over 512*512
    int c = idx >> 9, k = idx & 511;
    WT[idx] = f2bf(W[k * CBND + c]);            // WT[c][k]
}

// ---------------- degree: d_i = sum_j adj_ij ; dinv = rsqrt(d+eps) ----------------
__global__ __launch_bounds__(512) void k_deg(const u16* __restrict__ bbn_bf,
                                             const float* __restrict__ s,
                                             float* __restrict__ dinv) {
    __shared__ float part[8][16];
    int ibase = blockIdx.x * 16;
    int tid = threadIdx.x;
    int w = tid >> 6, l = tid & 63, lg = l >> 4, lr = l & 15;

    bf16x8 afrag = *reinterpret_cast<const bf16x8*>(bbn_bf + (ibase + lr) * BBND + lg * 8);
    float si[4];
#pragma unroll
    for (int r = 0; r < 4; ++r) si[r] = s[ibase + lg * 4 + r];

    float dacc[4] = {0.f, 0.f, 0.f, 0.f};
    int j0 = w * (NROWS / 8);
    for (int jt = 0; jt < NROWS / 8; jt += 16) {
        int jb = j0 + jt;
        bf16x8 bfrag = *reinterpret_cast<const bf16x8*>(bbn_bf + (jb + lr) * BBND + lg * 8);
        f32x4 dot = MFMA16(afrag, bfrag, ZERO4);
        float sj = s[jb + lr];
#pragma unroll
        for (int r = 0; r < 4; ++r) dacc[r] += adj_eval(dot[r], si[r] + sj);
    }
#pragma unroll
    for (int off = 1; off < 16; off <<= 1)
#pragma unroll
        for (int r = 0; r < 4; ++r) dacc[r] += __shfl_xor(dacc[r], off, 64);

    if (lr == 0) {
#pragma unroll
        for (int r = 0; r < 4; ++r) part[w][lg * 4 + r] = dacc[r];
    }
    __syncthreads();
    if (tid < 16) {
        float d = 0.f;
#pragma unroll
        for (int q = 0; q < 8; ++q) d += part[q][tid];
        dinv[ibase + tid] = rsqrtf(d + 1e-8f);
    }
}

// ---------------- fc: g_blk[(j>>3)*512 + c][j&7] = dinv_j * (cbn@W + b)[j][c] ----------------
__global__ __launch_bounds__(256) void k_fc(const float* __restrict__ cbn,
                                            const u16* __restrict__ WT,
                                            const float* __restrict__ bvec,
                                            const float* __restrict__ dinv,
                                            u16* __restrict__ g_blk) {
    int bid = blockIdx.x;
    int cb = bid & 7, jb = bid >> 3;
    int tid = threadIdx.x, w = tid >> 6, l = tid & 63, lg = l >> 4, lr = l & 15;
    int crow = cb * 64 + w * 16;
    int jcol = jb * 64;

    f32x4 acc[4];
#pragma unroll
    for (int f = 0; f < 4; ++f) acc[f] = ZERO4;

    for (int k0 = 0; k0 < CBND; k0 += 32) {
        bf16x8 afrag = *reinterpret_cast<const bf16x8*>(WT + (crow + lr) * CBND + k0 + lg * 8);
#pragma unroll
        for (int f = 0; f < 4; ++f) {
            const float* src = cbn + (jcol + f * 16 + lr) * CBND + k0 + lg * 8;
            f32x4 v0 = *reinterpret_cast<const f32x4*>(src);
            f32x4 v1 = *reinterpret_cast<const f32x4*>(src + 4);
            bf16x8 bfrag;
#pragma unroll
            for (int e = 0; e < 4; ++e) { bfrag[e] = (__bf16)v0[e]; bfrag[e + 4] = (__bf16)v1[e]; }
            acc[f] = MFMA16(afrag, bfrag, acc[f]);
        }
    }
#pragma unroll
    for (int f = 0; f < 4; ++f) {
#pragma unroll
        for (int r = 0; r < 4; ++r) {
            int c = crow + lg * 4 + r;
            int j = jcol + f * 16 + lr;
            float val = acc[f][r] + bvec[c];
            g_blk[(((j >> 3) * 512 + c) << 3) + (j & 7)] = f2bf(val * dinv[j]);
        }
    }
}

// ---------------- conv: atomic-accumulate sum_j adj_ij * g[:,j] into out ----------------
// Round-6 structure verbatim EXCEPT the B datapath reads the j-octet-blocked
// g_blk layout: one b128 load = two contiguous 512B segments (coalesced), vs
// 32 scattered 32B transactions from gT[c][j]. Values bit-identical.
// Grid 1024 = 128 i-tiles x 8 j-slices; jq = bx&7 so each XCD's resident
// blocks share one 1MB g-slice (L2-resident per XCD).

#define LOADB(T, R) { \
    const char* p = gB + (T) * 32768; \
    R##0 = *reinterpret_cast<const u32x4*>(p); \
    R##1 = *reinterpret_cast<const u32x4*>(p + 512); \
    R##2 = *reinterpret_cast<const u32x4*>(p + 1024); \
    R##3 = *reinterpret_cast<const u32x4*>(p + 1536); \
    R##4 = *reinterpret_cast<const u32x4*>(p + 16384); \
    R##5 = *reinterpret_cast<const u32x4*>(p + 16384 + 512); \
    R##6 = *reinterpret_cast<const u32x4*>(p + 16384 + 1024); \
    R##7 = *reinterpret_cast<const u32x4*>(p + 16384 + 1536); \
}

#define GEN(T, WB) { \
    int jg = jbase + (T) * JSTEP + jh2 * 16; \
    bf16x8 fJ = *reinterpret_cast<const bf16x8*>(bbn_bf + (jg + lr) * BBND + lg * 8); \
    f32x4 sj = *reinterpret_cast<const f32x4*>(s + jg + lg * 4); \
    f32x4 dot = MFMA16(fJ, fragI, ZERO4); \
    u32 p0 = cvtpk(adj_eval(dot[0], si + sj[0]), adj_eval(dot[1], si + sj[1])); \
    u32 p1 = cvtpk(adj_eval(dot[2], si + sj[2]), adj_eval(dot[3], si + sj[3])); \
    *reinterpret_cast<u32x2*>(Ab + (WB) * ABUFB + gw) = (u32x2){p0, p1}; \
}

#define CONV(RB, R) { \
    const char* Ar = Ab + (RB) * ABUFB; \
    bf16x8 a0 = *reinterpret_cast<const bf16x8*>(Ar + aoff0); \
    bf16x8 a1 = *reinterpret_cast<const bf16x8*>(Ar + aoff1); \
    acc0 = MFMA32(a0, __builtin_bit_cast(bf16x8, R##0), acc0); \
    acc1 = MFMA32(a0, __builtin_bit_cast(bf16x8, R##1), acc1); \
    acc2 = MFMA32(a0, __builtin_bit_cast(bf16x8, R##2), acc2); \
    acc3 = MFMA32(a0, __builtin_bit_cast(bf16x8, R##3), acc3); \
    acc0 = MFMA32(a1, __builtin_bit_cast(bf16x8, R##4), acc0); \
    acc1 = MFMA32(a1, __builtin_bit_cast(bf16x8, R##5), acc1); \
    acc2 = MFMA32(a1, __builtin_bit_cast(bf16x8, R##6), acc2); \
    acc3 = MFMA32(a1, __builtin_bit_cast(bf16x8, R##7), acc3); \
}

#define EPI(ACC, NC) { \
    _Pragma("unroll") \
    for (int reg = 0; reg < 16; ++reg) { \
        int rowD = (reg & 3) + 8 * (reg >> 2) + 4 * lh; \
        unsafeAtomicAdd(out + (long)(ibase + iw * 32 + rowD) * CBND \
                            + cw * 128 + (NC) * 32 + l31, ACC[reg]); \
    } \
}

__global__ __launch_bounds__(512, 2) void k_conv(const u16* __restrict__ bbn_bf,
                                                 const float* __restrict__ s,
                                                 const u16* __restrict__ g_blk,
                                                 float* __restrict__ out) {
    __shared__ __align__(16) u16 Alds[2][64 * 32];

    int bx = blockIdx.x;
    int jq = bx & 7;                   // XCD x's blocks share one 1MB g j-slice
    int it = bx >> 3;                  // 0..127
    int ibase = it * 64;
    int jbase = jq * JQ;

    int tid = threadIdx.x;
    int w = tid >> 6, l = tid & 63;
    int lr = l & 15, lg = l >> 4, l31 = l & 31, lh = l >> 5;
    int iw = w & 1, cw = w >> 1;       // acc wave tile: 32i x 128c
    int iqg = w & 3, jh2 = w >> 2;     // gen wave tile: 16i x 16j

    // gen hoists
    bf16x8 fragI = *reinterpret_cast<const bf16x8*>(bbn_bf + (ibase + iqg * 16 + lr) * BBND + lg * 8);
    float si = s[ibase + iqg * 16 + lr];

    char* Ab = (char*)&Alds[0][0];

    // B global base: byte addr of ((jbase/8 + lh)*512 + cw*128 + l31) * 16
    const char* gB = (const char*)g_blk + (long)jbase * 1024 + lh * 8192
                   + (cw * 128 + l31) * 16;

    // A-frag reads (swizzle: phys slot = logical ^ ((row>>1)&3))
    int arow = iw * 32 + l31;
    int sa = (arow >> 1) & 3;
    int aoff0 = arow * 64 + (((lh)     ^ sa) << 4);
    int aoff1 = arow * 64 + (((2 + lh) ^ sa) << 4);

    // gen write: row = iqg*16+lr, logical slot jh2*2+(lg>>1), byte +(lg&1)*8
    int grow = iqg * 16 + lr;
    int gw = grow * 64 + ((((jh2 * 2) + (lg >> 1)) ^ ((grow >> 1) & 3)) << 4) + (lg & 1) * 8;

    f32x16 acc0 = ZERO16, acc1 = ZERO16, acc2 = ZERO16, acc3 = ZERO16;

    u32x4 rA0, rA1, rA2, rA3, rA4, rA5, rA6, rA7;
    u32x4 rB0, rB1, rB2, rB3, rB4, rB5, rB6, rB7;

    // prologue: A(0) into buf0, B(0) into rA
    GEN(0, 0);
    LOADB(0, rA);
    __syncthreads();

    for (int t2 = 0; t2 < NTQ; t2 += 2) {
        // iter t2: rA = B(t2), buf0 = A(t2)
        LOADB(t2 + 1, rB);
        GEN(t2 + 1, 1);
        CONV(0, rA);
        __syncthreads();
        // iter t2+1: rB = B(t2+1), buf1 = A(t2+1)
        int tn = (t2 + 2 < NTQ) ? t2 + 2 : NTQ - 1;   // tail: redundant, never read
        LOADB(tn, rA);
        GEN(tn, 0);
        CONV(1, rB);
        __syncthreads();
    }

    EPI(acc0, 0);  EPI(acc1, 1);  EPI(acc2, 2);  EPI(acc3, 3);
}

// ---------------- sigmoid epilogue: out = sigmoid(dinv_i * out), in place ----------------
__global__ __launch_bounds__(256) void k_sig(const float* __restrict__ dinv,
                                             float* __restrict__ out) {
    int idx = blockIdx.x * 256 + threadIdx.x;   // f32x4 index; 1,048,576 total
    float di = dinv[idx >> 7];
    f32x4 v = *reinterpret_cast<const f32x4*>(out + idx * 4);
#pragma unroll
    for (int e = 0; e < 4; ++e) v[e] = sigmoidf_fast(v[e] * di);
    *reinterpret_cast<f32x4*>(out + idx * 4) = v;
}

extern "C" void kernel_launch(void* const* d_in, const int* in_sizes, int n_in,
                              void* d_out, int out_size, void* d_ws, size_t ws_size,
                              hipStream_t stream) {
    const float* bbn = (const float*)d_in[0];   // [8192,32]
    const float* cbn = (const float*)d_in[1];   // [8192,512]
    const float* W   = (const float*)d_in[2];   // [512,512]
    const float* b   = (const float*)d_in[3];   // [512]
    float* out = (float*)d_out;                 // [8192,512] f32

    char* ws = (char*)d_ws;
    float* s      = (float*)ws;  ws += NROWS * 4;
    float* dinv   = (float*)ws;  ws += NROWS * 4;
    u16* bbn_bf   = (u16*)ws;    ws += NROWS * BBND * 2;
    u16* WT       = (u16*)ws;    ws += CBND * CBND * 2;
    u16* g_blk    = (u16*)ws;    ws += CBND * NROWS * 2;

    hipMemsetAsync(d_out, 0, (size_t)out_size * sizeof(float), stream);
    k_prep_rows<<<NROWS / 256, 256, 0, stream>>>(bbn, s, bbn_bf);
    k_prep_wt<<<(CBND * CBND) / 256, 256, 0, stream>>>(W, WT);
    k_deg<<<NROWS / 16, 512, 0, stream>>>(bbn_bf, s, dinv);
    k_fc<<<(NROWS / 64) * (CBND / 64), 256, 0, stream>>>(cbn, WT, b, dinv, g_blk);
    k_conv<<<(NROWS / 64) * 8, 512, 0, stream>>>(bbn_bf, s, g_blk, out);
    k_sig<<<(NROWS * CBND / 4) / 256, 256, 0, stream>>>(dinv, out);
}

// Round 8
// 260.944 us; speedup vs baseline: 1.6034x; 1.1096x over previous
//
#include <hip/hip_runtime.h>

#define NROWS 8192
#define BBND  32
#define CBND  512
#define JQ    1024            // j-range per block (8 slices)
#define JSTEP 32
#define NTQ   (JQ / JSTEP)    // 32 iters
#define ABUFB 4096            // A LDS buffer bytes (64 rows x 64B)

typedef unsigned short u16;
typedef unsigned int   u32;
typedef __bf16 bf16x8 __attribute__((ext_vector_type(8)));
typedef float  f32x4  __attribute__((ext_vector_type(4)));
typedef float  f32x16 __attribute__((ext_vector_type(16)));
typedef u32    u32x4  __attribute__((ext_vector_type(4)));
typedef u32    u32x2  __attribute__((ext_vector_type(2)));

#define ZERO4  (f32x4){0.f,0.f,0.f,0.f}
#define ZERO16 (f32x16){0.f,0.f,0.f,0.f,0.f,0.f,0.f,0.f,0.f,0.f,0.f,0.f,0.f,0.f,0.f,0.f}

// raw barrier: drain LDS ops, keep global loads in flight (no vmcnt drain)
#define BAR asm volatile("s_waitcnt lgkmcnt(0)\n\ts_barrier" ::: "memory")

static __device__ inline u16 f2bf(float f) {
    unsigned u = __builtin_bit_cast(unsigned, f);
    unsigned r = (u + 0x7FFFu + ((u >> 16) & 1u)) >> 16;
    return (u16)r;
}

static __device__ inline float pow14(float base) {
    return __builtin_amdgcn_exp2f(1.4f * __builtin_amdgcn_logf(base));
}

static __device__ inline float adj_eval(float dot, float sij) {
    float x = fabsf(2.f * dot - sij);
    float base = fmaxf(1.f - x * (1.f / 32.f), 0.f);
    return pow14(base);
}

static __device__ inline float sigmoidf_fast(float v) {
    float e = __builtin_amdgcn_exp2f(-1.44269504f * v);
    return 1.f / (1.f + e);
}

static __device__ inline u32 cvtpk(float a, float b) {
    u32 r;
    asm("v_cvt_pk_bf16_f32 %0, %1, %2" : "=v"(r) : "v"(a), "v"(b));
    return r;
}

static __device__ inline f32x4 MFMA16(bf16x8 a, bf16x8 b, f32x4 c) {
    return __builtin_amdgcn_mfma_f32_16x16x32_bf16(a, b, c, 0, 0, 0);
}
static __device__ inline f32x16 MFMA32(bf16x8 a, bf16x8 b, f32x16 c) {
    return __builtin_amdgcn_mfma_f32_32x32x16_bf16(a, b, c, 0, 0, 0);
}

// ---------------- prep: row sums of bbn + bf16 copy ----------------
__global__ __launch_bounds__(256) void k_prep_rows(const float* __restrict__ bbn,
                                                   float* __restrict__ s,
                                                   u16* __restrict__ bbn_bf) {
    int i = blockIdx.x * 256 + threadIdx.x;
    if (i >= NROWS) return;
    const f32x4* row = reinterpret_cast<const f32x4*>(bbn + i * BBND);
    float sum = 0.f;
    u16* dst = bbn_bf + i * BBND;
#pragma unroll
    for (int q = 0; q < 8; ++q) {
        f32x4 v = row[q];
#pragma unroll
        for (int e = 0; e < 4; ++e) {
            sum += v[e];
            dst[q * 4 + e] = f2bf(v[e]);
        }
    }
    s[i] = sum;
}

// ---------------- prep: W transpose -> bf16 ----------------
__global__ __launch_bounds__(256) void k_prep_wt(const float* __restrict__ W,
                                                 u16* __restrict__ WT) {
    int idx = blockIdx.x * 256 + threadIdx.x;   // over 512*512
    int c = idx >> 9, k = idx & 511;
    WT[idx] = f2bf(W[k * CBND + c]);            // WT[c][k]
}

// ---------------- degree: d_i = sum_j adj_ij ; dinv = rsqrt(d+eps) ----------------
__global__ __launch_bounds__(512) void k_deg(const u16* __restrict__ bbn_bf,
                                             const float* __restrict__ s,
                                             float* __restrict__ dinv) {
    __shared__ float part[8][16];
    int ibase = blockIdx.x * 16;
    int tid = threadIdx.x;
    int w = tid >> 6, l = tid & 63, lg = l >> 4, lr = l & 15;

    bf16x8 afrag = *reinterpret_cast<const bf16x8*>(bbn_bf + (ibase + lr) * BBND + lg * 8);
    float si[4];
#pragma unroll
    for (int r = 0; r < 4; ++r) si[r] = s[ibase + lg * 4 + r];

    float dacc[4] = {0.f, 0.f, 0.f, 0.f};
    int j0 = w * (NROWS / 8);
    for (int jt = 0; jt < NROWS / 8; jt += 16) {
        int jb = j0 + jt;
        bf16x8 bfrag = *reinterpret_cast<const bf16x8*>(bbn_bf + (jb + lr) * BBND + lg * 8);
        f32x4 dot = MFMA16(afrag, bfrag, ZERO4);
        float sj = s[jb + lr];
#pragma unroll
        for (int r = 0; r < 4; ++r) dacc[r] += adj_eval(dot[r], si[r] + sj);
    }
#pragma unroll
    for (int off = 1; off < 16; off <<= 1)
#pragma unroll
        for (int r = 0; r < 4; ++r) dacc[r] += __shfl_xor(dacc[r], off, 64);

    if (lr == 0) {
#pragma unroll
        for (int r = 0; r < 4; ++r) part[w][lg * 4 + r] = dacc[r];
    }
    __syncthreads();
    if (tid < 16) {
        float d = 0.f;
#pragma unroll
        for (int q = 0; q < 8; ++q) d += part[q][tid];
        dinv[ibase + tid] = rsqrtf(d + 1e-8f);
    }
}

// ---------------- fc: g_blk[(j>>3)*512 + c][j&7] = dinv_j * (cbn@W + b)[j][c] ----------------
__global__ __launch_bounds__(256) void k_fc(const float* __restrict__ cbn,
                                            const u16* __restrict__ WT,
                                            const float* __restrict__ bvec,
                                            const float* __restrict__ dinv,
                                            u16* __restrict__ g_blk) {
    int bid = blockIdx.x;
    int cb = bid & 7, jb = bid >> 3;
    int tid = threadIdx.x, w = tid >> 6, l = tid & 63, lg = l >> 4, lr = l & 15;
    int crow = cb * 64 + w * 16;
    int jcol = jb * 64;

    f32x4 acc[4];
#pragma unroll
    for (int f = 0; f < 4; ++f) acc[f] = ZERO4;

    for (int k0 = 0; k0 < CBND; k0 += 32) {
        bf16x8 afrag = *reinterpret_cast<const bf16x8*>(WT + (crow + lr) * CBND + k0 + lg * 8);
#pragma unroll
        for (int f = 0; f < 4; ++f) {
            const float* src = cbn + (jcol + f * 16 + lr) * CBND + k0 + lg * 8;
            f32x4 v0 = *reinterpret_cast<const f32x4*>(src);
            f32x4 v1 = *reinterpret_cast<const f32x4*>(src + 4);
            bf16x8 bfrag;
#pragma unroll
            for (int e = 0; e < 4; ++e) { bfrag[e] = (__bf16)v0[e]; bfrag[e + 4] = (__bf16)v1[e]; }
            acc[f] = MFMA16(afrag, bfrag, acc[f]);
        }
    }
#pragma unroll
    for (int f = 0; f < 4; ++f) {
#pragma unroll
        for (int r = 0; r < 4; ++r) {
            int c = crow + lg * 4 + r;
            int j = jcol + f * 16 + lr;
            float val = acc[f][r] + bvec[c];
            g_blk[(((j >> 3) * 512 + c) << 3) + (j & 7)] = f2bf(val * dinv[j]);
        }
    }
}

// ---------------- conv: atomic-accumulate sum_j adj_ij * g[:,j] into out ----------------
// Round-7 structure with two changes:
//  (1) raw barrier (lgkmcnt drain only) -> global B prefetch survives the barrier
//  (2) wave tile 64i x 64c (was 32i x 128c): same 8 MFMA32/iter, same per-acc
//      k-order (bit-identical sums), but HALF the B loads (4 b128/thread/iter,
//      no iw duplication -> 1.05 GB total L2 reads).

#define LOADB(T, R) { \
    const char* p = gB + (T) * 32768; \
    R##0 = *reinterpret_cast<const u32x4*>(p); \
    R##1 = *reinterpret_cast<const u32x4*>(p + 512); \
    R##2 = *reinterpret_cast<const u32x4*>(p + 16384); \
    R##3 = *reinterpret_cast<const u32x4*>(p + 16384 + 512); \
}

#define GEN(T, WB) { \
    int jg = jbase + (T) * JSTEP + jh2 * 16; \
    bf16x8 fJ = *reinterpret_cast<const bf16x8*>(bbn_bf + (jg + lr) * BBND + lg * 8); \
    f32x4 sj = *reinterpret_cast<const f32x4*>(s + jg + lg * 4); \
    f32x4 dot = MFMA16(fJ, fragI, ZERO4); \
    u32 p0 = cvtpk(adj_eval(dot[0], si + sj[0]), adj_eval(dot[1], si + sj[1])); \
    u32 p1 = cvtpk(adj_eval(dot[2], si + sj[2]), adj_eval(dot[3], si + sj[3])); \
    *reinterpret_cast<u32x2*>(Ab + (WB) * ABUFB + gw) = (u32x2){p0, p1}; \
}

#define CONV(RB, R) { \
    const char* Ar = Ab + (RB) * ABUFB; \
    bf16x8 a00 = *reinterpret_cast<const bf16x8*>(Ar + aoff00); \
    bf16x8 a10 = *reinterpret_cast<const bf16x8*>(Ar + aoff00 + 2048); \
    acc00 = MFMA32(a00, __builtin_bit_cast(bf16x8, R##0), acc00); \
    acc01 = MFMA32(a00, __builtin_bit_cast(bf16x8, R##1), acc01); \
    acc10 = MFMA32(a10, __builtin_bit_cast(bf16x8, R##0), acc10); \
    acc11 = MFMA32(a10, __builtin_bit_cast(bf16x8, R##1), acc11); \
    bf16x8 a01 = *reinterpret_cast<const bf16x8*>(Ar + aoff01); \
    bf16x8 a11 = *reinterpret_cast<const bf16x8*>(Ar + aoff01 + 2048); \
    acc00 = MFMA32(a01, __builtin_bit_cast(bf16x8, R##2), acc00); \
    acc01 = MFMA32(a01, __builtin_bit_cast(bf16x8, R##3), acc01); \
    acc10 = MFMA32(a11, __builtin_bit_cast(bf16x8, R##2), acc10); \
    acc11 = MFMA32(a11, __builtin_bit_cast(bf16x8, R##3), acc11); \
}

#define EPI(ACC, IT, CT) { \
    _Pragma("unroll") \
    for (int reg = 0; reg < 16; ++reg) { \
        int rowD = (reg & 3) + 8 * (reg >> 2) + 4 * lh; \
        unsafeAtomicAdd(out + (long)(ibase + (IT) * 32 + rowD) * CBND \
                            + w * 64 + (CT) * 32 + l31, ACC[reg]); \
    } \
}

__global__ __launch_bounds__(512, 2) void k_conv(const u16* __restrict__ bbn_bf,
                                                 const float* __restrict__ s,
                                                 const u16* __restrict__ g_blk,
                                                 float* __restrict__ out) {
    __shared__ __align__(16) u16 Alds[2][64 * 32];

    int bx = blockIdx.x;
    int jq = bx & 7;                   // XCD x's blocks share one 1MB g j-slice
    int it = bx >> 3;                  // 0..127
    int ibase = it * 64;
    int jbase = jq * JQ;

    int tid = threadIdx.x;
    int w = tid >> 6, l = tid & 63;
    int lr = l & 15, lg = l >> 4, l31 = l & 31, lh = l >> 5;
    int iqg = w & 3, jh2 = w >> 2;     // gen wave tile: 16i x 16j

    // gen hoists
    bf16x8 fragI = *reinterpret_cast<const bf16x8*>(bbn_bf + (ibase + iqg * 16 + lr) * BBND + lg * 8);
    float si = s[ibase + iqg * 16 + lr];

    char* Ab = (char*)&Alds[0][0];

    // B global base: octet (jbase/8 + T*4 + lh), c = w*64 (+CT*32) + l31
    const char* gB = (const char*)g_blk + (long)jbase * 1024 + lh * 8192
                   + (w * 64 + l31) * 16;

    // A-frag reads (swizzle: phys slot = logical ^ ((row>>1)&3)); rows l31 / l31+32
    int sa = (l31 >> 1) & 3;           // same for row l31+32 (32>>1=16, 16&3=0)
    int aoff00 = l31 * 64 + (((lh)     ^ sa) << 4);   // k-step 0; +2048 -> row+32
    int aoff01 = l31 * 64 + (((2 + lh) ^ sa) << 4);   // k-step 1

    // gen write: row = iqg*16+lr, logical slot jh2*2+(lg>>1), byte +(lg&1)*8
    int grow = iqg * 16 + lr;
    int gw = grow * 64 + ((((jh2 * 2) + (lg >> 1)) ^ ((grow >> 1) & 3)) << 4) + (lg & 1) * 8;

    f32x16 acc00 = ZERO16, acc01 = ZERO16, acc10 = ZERO16, acc11 = ZERO16;

    u32x4 rA0, rA1, rA2, rA3;
    u32x4 rB0, rB1, rB2, rB3;

    // prologue: A(0) into buf0, B(0) into rA
    GEN(0, 0);
    LOADB(0, rA);
    BAR;

    for (int t2 = 0; t2 < NTQ; t2 += 2) {
        // iter t2: rA = B(t2), buf0 = A(t2)
        LOADB(t2 + 1, rB);
        GEN(t2 + 1, 1);
        CONV(0, rA);
        BAR;
        // iter t2+1: rB = B(t2+1), buf1 = A(t2+1)
        int tn = (t2 + 2 < NTQ) ? t2 + 2 : NTQ - 1;   // tail: redundant, never read
        LOADB(tn, rA);
        GEN(tn, 0);
        CONV(1, rB);
        BAR;
    }

    EPI(acc00, 0, 0);  EPI(acc01, 0, 1);  EPI(acc10, 1, 0);  EPI(acc11, 1, 1);
}

// ---------------- sigmoid epilogue: out = sigmoid(dinv_i * out), in place ----------------
__global__ __launch_bounds__(256) void k_sig(const float* __restrict__ dinv,
                                             float* __restrict__ out) {
    int idx = blockIdx.x * 256 + threadIdx.x;   // f32x4 index; 1,048,576 total
    float di = dinv[idx >> 7];
    f32x4 v = *reinterpret_cast<const f32x4*>(out + idx * 4);
#pragma unroll
    for (int e = 0; e < 4; ++e) v[e] = sigmoidf_fast(v[e] * di);
    *reinterpret_cast<f32x4*>(out + idx * 4) = v;
}

extern "C" void kernel_launch(void* const* d_in, const int* in_sizes, int n_in,
                              void* d_out, int out_size, void* d_ws, size_t ws_size,
                              hipStream_t stream) {
    const float* bbn = (const float*)d_in[0];   // [8192,32]
    const float* cbn = (const float*)d_in[1];   // [8192,512]
    const float* W   = (const float*)d_in[2];   // [512,512]
    const float* b   = (const float*)d_in[3];   // [512]
    float* out = (float*)d_out;                 // [8192,512] f32

    char* ws = (char*)d_ws;
    float* s      = (float*)ws;  ws += NROWS * 4;
    float* dinv   = (float*)ws;  ws += NROWS * 4;
    u16* bbn_bf   = (u16*)ws;    ws += NROWS * BBND * 2;
    u16* WT       = (u16*)ws;    ws += CBND * CBND * 2;
    u16* g_blk    = (u16*)ws;    ws += CBND * NROWS * 2;

    hipMemsetAsync(d_out, 0, (size_t)out_size * sizeof(float), stream);
    k_prep_rows<<<NROWS / 256, 256, 0, stream>>>(bbn, s, bbn_bf);
    k_prep_wt<<<(CBND * CBND) / 256, 256, 0, stream>>>(W, WT);
    k_deg<<<NROWS / 16, 512, 0, stream>>>(bbn_bf, s, dinv);
    k_fc<<<(NROWS / 64) * (CBND / 64), 256, 0, stream>>>(cbn, WT, b, dinv, g_blk);
    k_conv<<<(NROWS / 64) * 8, 512, 0, stream>>>(bbn_bf, s, g_blk, out);
    k_sig<<<(NROWS * CBND / 4) / 256, 256, 0, stream>>>(dinv, out);
}